// Round 6
// baseline (1216.733 us; speedup 1.0000x reference)
//
#include <hip/hip_runtime.h>
#include <float.h>

#define D 512
#define QB 64           // queries per block (B operand / N dim)
#define PW 128          // points per wave (A operand / M dim)
#define PT 512          // points per block-tile (4 waves)
#define NCH 32          // chunks over the point dim
#define MPCL 3          // per-lane-cell candidate list
#define MPC 8           // candidates kept per (query, chunk)
#define TR 16           // candidates exactly rescored per query

typedef __attribute__((ext_vector_type(8))) short short8;
typedef __attribute__((ext_vector_type(4))) float f32x4;

__device__ __forceinline__ unsigned short f2bf(float f) {
    unsigned u = __float_as_uint(f);
    return (unsigned short)((u + 0x7FFF + ((u >> 16) & 1)) >> 16);
}

template <int K>
__device__ __forceinline__ void insertK(float* bs, int* bi, float v, int id) {
    if (v < bs[K - 1]) {
        bs[K - 1] = v; bi[K - 1] = id;
#pragma unroll
        for (int r = K - 1; r >= 1; --r) {
            if (bs[r] < bs[r - 1]) {
                float tf = bs[r]; bs[r] = bs[r - 1]; bs[r - 1] = tf;
                int ti = bi[r]; bi[r] = bi[r - 1]; bi[r - 1] = ti;
            }
        }
    }
}

// X fp32 -> bf16 (zero-padded rows) + exact fp32 ||x||^2 (1e30 for pad rows).
__global__ void convert_x(const float* __restrict__ X, unsigned short* __restrict__ Xbf,
                          float* __restrict__ xsq, int N, int padN) {
    int row = blockIdx.x * 4 + (threadIdx.x >> 6);
    int lane = threadIdx.x & 63;
    if (row >= padN) return;
    unsigned short ob[8];
    float s = 0.0f;
    if (row < N) {
        const float* p = X + (size_t)row * D + lane * 8;
        float4 a = *(const float4*)p;
        float4 b = *(const float4*)(p + 4);
        s = a.x * a.x + a.y * a.y + a.z * a.z + a.w * a.w
          + b.x * b.x + b.y * b.y + b.z * b.z + b.w * b.w;
        ob[0] = f2bf(a.x); ob[1] = f2bf(a.y); ob[2] = f2bf(a.z); ob[3] = f2bf(a.w);
        ob[4] = f2bf(b.x); ob[5] = f2bf(b.y); ob[6] = f2bf(b.z); ob[7] = f2bf(b.w);
    } else {
#pragma unroll
        for (int i = 0; i < 8; ++i) ob[i] = 0;
    }
    *(uint4*)(Xbf + (size_t)row * D + lane * 8) = *(uint4*)ob;
#pragma unroll
    for (int off = 32; off > 0; off >>= 1) s += __shfl_down(s, off, 64);
    if (lane == 0) xsq[row] = (row < N) ? s : 1e30f;
}

// Q fp32 -> bf16(-2*q).
__global__ void convert_q(const float* __restrict__ Q, unsigned short* __restrict__ Qbf) {
    int row = blockIdx.x * 4 + (threadIdx.x >> 6);
    int lane = threadIdx.x & 63;
    const float* p = Q + (size_t)row * D + lane * 8;
    float4 a = *(const float4*)p;
    float4 b = *(const float4*)(p + 4);
    unsigned short ob[8];
    ob[0] = f2bf(-2.0f * a.x); ob[1] = f2bf(-2.0f * a.y);
    ob[2] = f2bf(-2.0f * a.z); ob[3] = f2bf(-2.0f * a.w);
    ob[4] = f2bf(-2.0f * b.x); ob[5] = f2bf(-2.0f * b.y);
    ob[6] = f2bf(-2.0f * b.z); ob[7] = f2bf(-2.0f * b.w);
    *(uint4*)(Qbf + (size_t)row * D + lane * 8) = *(uint4*)ob;
}

// Transposed MFMA scorer: A = X (128 points/wave), B = Q (64 queries, LDS-resident).
// XCD-packed grid: all 32 qt-blocks of a chunk on one XCD -> X slice L2-resident.
// Selection fully in registers; no barriers in the tile loop.
__global__ __launch_bounds__(256, 2) void score_mfma(
    const unsigned short* __restrict__ Qbf,
    const unsigned short* __restrict__ Xbf,
    const float* __restrict__ xsq,
    float* __restrict__ candS, int* __restrict__ candI,
    int ntiles)
{
    __shared__ union {
        unsigned short Qs[QB * D];                                   // 64 KB
        struct { float ms[QB][16][MPCL]; int mi[QB][16][MPCL]; } mg; // 24 KB
    } u;

    const int tid = threadIdx.x;
    const int wave = tid >> 6;
    const int lane = tid & 63;
    const int quad = lane >> 4;
    const int l15 = lane & 15;

    // XCD packing: xcd = bid&7 owns chunks [xcd*4, xcd*4+4); qt fastest.
    const int bid = blockIdx.x;
    const int xcd = bid & 7;
    const int s_ = bid >> 3;
    const int chunk = xcd * 4 + (s_ >> 5);
    const int qt = s_ & 31;
    const int t0 = (chunk * ntiles) / NCH;
    const int t1 = ((chunk + 1) * ntiles) / NCH;

    // ---- stage Q once, k-segment XOR-swizzled by row (conflict-free reads) ----
    {
        const unsigned short* qg = Qbf + (size_t)qt * QB * D;
#pragma unroll
        for (int i = 0; i < 16; ++i) {
            int flat = i * 256 + tid;     // 4096 segments of 8 elems
            int r = flat >> 6;
            int sg = flat & 63;
            uint4 v = *(const uint4*)(qg + (size_t)r * D + sg * 8);
            *(uint4*)&u.Qs[r * D + (sg ^ (r & 7)) * 8] = v;
        }
    }
    __syncthreads();

    float ls[4][MPCL]; int li[4][MPCL];
#pragma unroll
    for (int tj = 0; tj < 4; ++tj)
#pragma unroll
        for (int r = 0; r < MPCL; ++r) { ls[tj][r] = FLT_MAX; li[tj][r] = -1; }

    for (int tile = t0; tile < t1; ++tile) {
        const int pb = tile * PT + wave * PW;   // this wave's 128 points
        const unsigned short* xp = Xbf + (size_t)(pb + l15) * D + quad * 8;

        f32x4 acc[8][4];
#pragma unroll
        for (int ti = 0; ti < 8; ++ti)
#pragma unroll
            for (int tj = 0; tj < 4; ++tj) acc[ti][tj] = (f32x4){0.f, 0.f, 0.f, 0.f};

        // 2-deep X-fragment pipeline: x0 even k0, x1 odd k0 (prefetch kk+2)
        short8 x0[8], x1[8];
#pragma unroll
        for (int ti = 0; ti < 8; ++ti) x0[ti] = *(const short8*)(xp + (size_t)ti * 16 * D);
#pragma unroll
        for (int ti = 0; ti < 8; ++ti) x1[ti] = *(const short8*)(xp + (size_t)ti * 16 * D + 32);

#pragma unroll
        for (int kk = 0; kk < 8; ++kk) {
            // even k0 = 2kk
#pragma unroll
            for (int tj = 0; tj < 4; ++tj) {
                int r = tj * 16 + l15;
                int seg = ((2 * kk) * 4 + quad) ^ (r & 7);
                short8 qf = *(const short8*)&u.Qs[r * D + seg * 8];
#pragma unroll
                for (int ti = 0; ti < 8; ++ti)
                    acc[ti][tj] = __builtin_amdgcn_mfma_f32_16x16x32_bf16(
                        x0[ti], qf, acc[ti][tj], 0, 0, 0);
            }
            if (kk < 7) {
#pragma unroll
                for (int ti = 0; ti < 8; ++ti)
                    x0[ti] = *(const short8*)(xp + (size_t)ti * 16 * D + (2 * kk + 2) * 32);
            }
            // odd k0 = 2kk+1
#pragma unroll
            for (int tj = 0; tj < 4; ++tj) {
                int r = tj * 16 + l15;
                int seg = ((2 * kk + 1) * 4 + quad) ^ (r & 7);
                short8 qf = *(const short8*)&u.Qs[r * D + seg * 8];
#pragma unroll
                for (int ti = 0; ti < 8; ++ti)
                    acc[ti][tj] = __builtin_amdgcn_mfma_f32_16x16x32_bf16(
                        x1[ti], qf, acc[ti][tj], 0, 0, 0);
            }
            if (kk < 7) {
#pragma unroll
                for (int ti = 0; ti < 8; ++ti)
                    x1[ti] = *(const short8*)(xp + (size_t)ti * 16 * D + (2 * kk + 3) * 32);
            }
        }

        // selection: point = pb + ti*16 + quad*4 + rg, query = tj*16 + l15
#pragma unroll
        for (int ti = 0; ti < 8; ++ti) {
            float4 xs = *(const float4*)&xsq[pb + ti * 16 + quad * 4];
            float xsv[4] = {xs.x, xs.y, xs.z, xs.w};
#pragma unroll
            for (int tj = 0; tj < 4; ++tj)
#pragma unroll
                for (int rg = 0; rg < 4; ++rg)
                    insertK<MPCL>(ls[tj], li[tj], acc[ti][tj][rg] + xsv[rg],
                                  pb + ti * 16 + quad * 4 + rg);
        }
    }

    // ---- block merge: 16 cell-lists per query -> top-8 per (query,chunk) ----
    __syncthreads();   // Q no longer needed; reuse LDS
#pragma unroll
    for (int tj = 0; tj < 4; ++tj)
#pragma unroll
        for (int r = 0; r < MPCL; ++r) {
            u.mg.ms[tj * 16 + l15][wave * 4 + quad][r] = ls[tj][r];
            u.mg.mi[tj * 16 + l15][wave * 4 + quad][r] = li[tj][r];
        }
    __syncthreads();
    if (tid < QB) {
        float fs[MPC]; int fi[MPC];
#pragma unroll
        for (int r = 0; r < MPC; ++r) { fs[r] = FLT_MAX; fi[r] = -1; }
        for (int c = 0; c < 16; ++c)
#pragma unroll
            for (int r = 0; r < MPCL; ++r)
                insertK<MPC>(fs, fi, u.mg.ms[tid][c][r], u.mg.mi[tid][c][r]);
        size_t base = ((size_t)(qt * QB + tid) * NCH + chunk) * MPC;
#pragma unroll
        for (int r = 0; r < MPC; ++r) { candS[base + r] = fs[r]; candI[base + r] = fi[r]; }
    }
}

// Per query: wave-parallel merge of NCH sorted chunk-lists -> approx top-16 ->
// exact fp32 rescore -> exact top-5 -> gather + mean.
__global__ void rescore_kernel(const float* __restrict__ Q, const float* __restrict__ X,
                               const float* __restrict__ xsq,
                               const float* __restrict__ candS, const int* __restrict__ candI,
                               float* __restrict__ out) {
    const int b = blockIdx.x;
    const int tid = threadIdx.x;
    const int wave = tid >> 6;
    const int lane = tid & 63;
    __shared__ int exI[TR];
    __shared__ float exS[TR];
    __shared__ int top5[5];

    if (wave == 0) {
        const float* cs = candS + (size_t)b * NCH * MPC;
        const int* ci = candI + (size_t)b * NCH * MPC;
        int h = 0;
        float cur = (lane < NCH) ? cs[lane * MPC] : FLT_MAX;
        for (int r = 0; r < TR; ++r) {
            float v = cur; int wl = lane;
#pragma unroll
            for (int off = 1; off < 64; off <<= 1) {
                float ov = __shfl_xor(v, off, 64);
                int owl = __shfl_xor(wl, off, 64);
                if (ov < v || (ov == v && owl < wl)) { v = ov; wl = owl; }
            }
            if (lane == wl) {
                exI[r] = ci[lane * MPC + h];
                ++h;
                cur = (h < MPC) ? cs[lane * MPC + h] : FLT_MAX;
            }
        }
    }
    __syncthreads();

    const float* qr = Q + (size_t)b * D;
#pragma unroll
    for (int cc = 0; cc < 4; ++cc) {
        int c = wave * 4 + cc;
        int idx = exI[c];
        const float* xr = X + (size_t)idx * D;
        float4 qa = *(const float4*)(qr + lane * 8);
        float4 qb = *(const float4*)(qr + lane * 8 + 4);
        float4 xa = *(const float4*)(xr + lane * 8);
        float4 xb = *(const float4*)(xr + lane * 8 + 4);
        float p = qa.x * xa.x + qa.y * xa.y + qa.z * xa.z + qa.w * xa.w
                + qb.x * xb.x + qb.y * xb.y + qb.z * xb.z + qb.w * xb.w;
#pragma unroll
        for (int off = 32; off > 0; off >>= 1) p += __shfl_down(p, off, 64);
        if (lane == 0) exS[c] = xsq[idx] - 2.0f * p;
    }
    __syncthreads();

    if (tid == 0) {
        float fs[5]; int fi[5];
#pragma unroll
        for (int r = 0; r < 5; ++r) { fs[r] = FLT_MAX; fi[r] = -1; }
        for (int i = 0; i < TR; ++i) insertK<5>(fs, fi, exS[i], exI[i]);
#pragma unroll
        for (int r = 0; r < 5; ++r) top5[r] = fi[r];
    }
    __syncthreads();

#pragma unroll
    for (int dd = 0; dd < 2; ++dd) {
        int d = tid + dd * 256;
        float s = 0.0f;
#pragma unroll
        for (int r = 0; r < 5; ++r) s += X[(size_t)top5[r] * D + d];
        out[(size_t)b * D + d] = s / 5.0f;
    }
}

extern "C" void kernel_launch(void* const* d_in, const int* in_sizes, int n_in,
                              void* d_out, int out_size, void* d_ws, size_t ws_size,
                              hipStream_t stream) {
    const float* x_enc = (const float*)d_in[0];
    const float* X_fit = (const float*)d_in[1];
    float* out = (float*)d_out;
    const int B = in_sizes[0] / D;               // 2048
    const int N = in_sizes[1] / D;               // 100000
    const int padN = ((N + PT - 1) / PT) * PT;   // 100352
    const int ntiles = padN / PT;                // 196
    const int qblocks = B / QB;                  // 32

    char* w = (char*)d_ws;
    unsigned short* Xbf = (unsigned short*)w;            w += (size_t)padN * D * 2;
    unsigned short* Qbf = (unsigned short*)w;            w += (size_t)B * D * 2;
    float* xsq = (float*)w;                              w += (size_t)padN * 4;
    float* candS = (float*)w;                            w += (size_t)B * NCH * MPC * 4;
    int* candI = (int*)w;

    hipLaunchKernelGGL(convert_x, dim3(padN / 4), dim3(256), 0, stream, X_fit, Xbf, xsq, N, padN);
    hipLaunchKernelGGL(convert_q, dim3(B / 4), dim3(256), 0, stream, x_enc, Qbf);
    hipLaunchKernelGGL(score_mfma, dim3(8 * 4 * qblocks), dim3(256), 0, stream,
                       Qbf, Xbf, xsq, candS, candI, ntiles);
    hipLaunchKernelGGL(rescore_kernel, dim3(B), dim3(256), 0, stream,
                       x_enc, X_fit, xsq, candS, candI, out);
}

// Round 7
// 1033.796 us; speedup vs baseline: 1.1770x; 1.1770x over previous
//
#include <hip/hip_runtime.h>
#include <float.h>

#define D 512
#define QB 64           // queries per block (B operand / N dim)
#define PW 112          // points per wave (A operand / M dim) = 7 frag rows
#define NTI 7
#define PT 448          // points per block-tile (4 waves)
#define TPC 4           // tiles per chunk (uniform)
#define NCH 56          // chunks: 56 * 4 * 448 = 100352 = padN
#define MPCL 3          // per-lane-cell candidate list
#define MPC 8           // candidates kept per (query, chunk)
#define TR 16           // candidates exactly rescored per query
#define CPQ (NCH * MPC) // 448 candidates per query

typedef __attribute__((ext_vector_type(4))) float f32x4;

// fp32 -> OCP e4m3fn (RNE, FTZ below 2^-6, clamp to 448). Only needs to be
// self-consistent (approx scores); exact fp32 rescore fixes the final answer.
__device__ __forceinline__ unsigned char f2fp8(float f) {
    unsigned u = __float_as_uint(f);
    unsigned s = (u >> 24) & 0x80u;
    unsigned a = u & 0x7FFFFFFFu;
    if (a < 0x3C800000u) return (unsigned char)s;            // |f| < 2^-6 -> +-0
    unsigned r = a + 0x7FFFFu + ((a >> 20) & 1u);            // RNE to 3 mantissa bits
    int e = (int)(r >> 23) - 127 + 7;
    unsigned m = (r >> 20) & 7u;
    if (e > 15) return (unsigned char)(s | 0x7Eu);           // clamp to 448
    return (unsigned char)(s | ((unsigned)e << 3) | m);
}

template <int K>
__device__ __forceinline__ void insertK(float* bs, int* bi, float v, int id) {
    if (v < bs[K - 1]) {
        bs[K - 1] = v; bi[K - 1] = id;
#pragma unroll
        for (int r = K - 1; r >= 1; --r) {
            if (bs[r] < bs[r - 1]) {
                float tf = bs[r]; bs[r] = bs[r - 1]; bs[r - 1] = tf;
                int ti = bi[r]; bi[r] = bi[r - 1]; bi[r - 1] = ti;
            }
        }
    }
}

// X fp32 -> fp8, tile-packed [pg=row/16][k0=k/32][row%16][32B] so one wave
// frag-load = contiguous 512B. Also exact fp32 ||x||^2 (1e30 for pad rows).
__global__ void convert_x(const float* __restrict__ X, unsigned char* __restrict__ Xp,
                          float* __restrict__ xsq, int N, int padN) {
    int row = blockIdx.x * 4 + (threadIdx.x >> 6);
    int lane = threadIdx.x & 63;
    if (row >= padN) return;
    float v[8]; float s = 0.0f;
    if (row < N) {
        const float* p = X + (size_t)row * D + lane * 8;
        float4 a = *(const float4*)p;
        float4 b = *(const float4*)(p + 4);
        s = a.x * a.x + a.y * a.y + a.z * a.z + a.w * a.w
          + b.x * b.x + b.y * b.y + b.z * b.z + b.w * b.w;
        v[0] = a.x; v[1] = a.y; v[2] = a.z; v[3] = a.w;
        v[4] = b.x; v[5] = b.y; v[6] = b.z; v[7] = b.w;
    } else {
#pragma unroll
        for (int i = 0; i < 8; ++i) v[i] = 0.0f;
    }
    unsigned long w = 0;
#pragma unroll
    for (int i = 0; i < 8; ++i) w |= (unsigned long)f2fp8(v[i]) << (8 * i);
    // lane covers k = lane*8..+8 -> k0-step ks = lane>>2, quad = lane&3
    size_t pg = (size_t)(row >> 4);
    int r16 = row & 15, ks = lane >> 2, qd = lane & 3;
    *(unsigned long*)(Xp + pg * 8192 + ks * 512 + r16 * 32 + qd * 8) = w;
#pragma unroll
    for (int off = 32; off > 0; off >>= 1) s += __shfl_down(s, off, 64);
    if (lane == 0) xsq[row] = (row < N) ? s : 1e30f;
}

// Q fp32 -> fp8(-2*q), row-linear.
__global__ void convert_q(const float* __restrict__ Q, unsigned char* __restrict__ Qp) {
    int row = blockIdx.x * 4 + (threadIdx.x >> 6);
    int lane = threadIdx.x & 63;
    const float* p = Q + (size_t)row * D + lane * 8;
    float4 a = *(const float4*)p;
    float4 b = *(const float4*)(p + 4);
    float v[8] = {a.x, a.y, a.z, a.w, b.x, b.y, b.z, b.w};
    unsigned long w = 0;
#pragma unroll
    for (int i = 0; i < 8; ++i) w |= (unsigned long)f2fp8(-2.0f * v[i]) << (8 * i);
    *(unsigned long*)(Qp + (size_t)row * D + lane * 8) = w;
}

// fp8 MFMA scorer: A = X (112 points/wave), B = Q (64 queries, LDS-resident fp8).
// X streams global->VGPR from a per-chunk slice (0.92 MB) pinned in one XCD's L2
// by the grid mapping; 3-deep prefetch rotation; selection in registers.
__global__ __launch_bounds__(256, 2) void score_mfma(
    const unsigned char* __restrict__ Qp,
    const unsigned char* __restrict__ Xp,
    const float* __restrict__ xsq,
    float* __restrict__ candS, int* __restrict__ candI)
{
    __shared__ union __align__(16) {
        unsigned char Qs[QB * 512];                                  // 32 KB
        struct { float ms[QB][16][MPCL]; int mi[QB][16][MPCL]; } mg; // 24 KB
    } u;

    const int tid = threadIdx.x;
    const int wave = tid >> 6;
    const int lane = tid & 63;
    const int quad = lane >> 4;
    const int l15 = lane & 15;

    // XCD packing: xcd = bid&7 owns 7 chunks; 32 qt-blocks per chunk, qt fastest.
    const int bid = blockIdx.x;
    const int xcd = bid & 7;
    const int s_ = bid >> 3;           // 0..223
    const int chunk = xcd * 7 + (s_ >> 5);
    const int qt = s_ & 31;

    // ---- stage Q once; 8B segment s of row r lands at LDS seg s^(r&15) ----
    {
        const unsigned char* qg = Qp + (size_t)qt * QB * 512;
#pragma unroll
        for (int i = 0; i < 16; ++i) {
            int flat = i * 256 + tid;           // 4096 8B-segments
            int r = flat >> 6, sg = flat & 63;
            unsigned long v = *(const unsigned long*)(qg + (size_t)r * 512 + sg * 8);
            *(unsigned long*)&u.Qs[r * 512 + (sg ^ (r & 15)) * 8] = v;
        }
    }
    __syncthreads();

    float ls[4][MPCL]; int li[4][MPCL];
#pragma unroll
    for (int tj = 0; tj < 4; ++tj)
#pragma unroll
        for (int r = 0; r < MPCL; ++r) { ls[tj][r] = FLT_MAX; li[tj][r] = -1; }

    for (int tt = 0; tt < TPC; ++tt) {
        const int tile = chunk * TPC + tt;
        const int pb = tile * PT + wave * PW;       // this wave's 112 points
        const unsigned char* xpb = Xp + ((size_t)(pb >> 4)) * 8192 + l15 * 32 + quad * 8;

        f32x4 acc[NTI][4];
#pragma unroll
        for (int ti = 0; ti < NTI; ++ti)
#pragma unroll
            for (int tj = 0; tj < 4; ++tj) acc[ti][tj] = (f32x4){0.f, 0.f, 0.f, 0.f};

        // 3-deep k0 rotation: up to 21 loads in flight, ~2.8 k0-steps of lead
        unsigned long xb[3][NTI];
#pragma unroll
        for (int b = 0; b < 3; ++b)
#pragma unroll
            for (int ti = 0; ti < NTI; ++ti)
                xb[b][ti] = *(const unsigned long*)(xpb + (size_t)ti * 8192 + b * 512);

        float4 xs[NTI];
#pragma unroll
        for (int kk = 0; kk < 16; ++kk) {
            const int b = kk % 3;
#pragma unroll
            for (int tj = 0; tj < 4; ++tj) {
                int r = tj * 16 + l15;
                int seg = (kk * 4 + quad) ^ (r & 15);
                long qf = *(const long*)&u.Qs[r * 512 + seg * 8];
#pragma unroll
                for (int ti = 0; ti < NTI; ++ti)
                    acc[ti][tj] = __builtin_amdgcn_mfma_f32_16x16x32_fp8_fp8(
                        (long)xb[b][ti], qf, acc[ti][tj], 0, 0, 0);
            }
            if (kk < 13) {
#pragma unroll
                for (int ti = 0; ti < NTI; ++ti)
                    xb[b][ti] = *(const unsigned long*)(xpb + (size_t)ti * 8192 + (kk + 3) * 512);
            }
            if (kk == 12) {   // prefetch xsq for the selection stage (~3 steps lead)
#pragma unroll
                for (int ti = 0; ti < NTI; ++ti)
                    xs[ti] = *(const float4*)&xsq[pb + ti * 16 + quad * 4];
            }
        }

        // selection: point = pb + ti*16 + quad*4 + rg, query = tj*16 + l15
#pragma unroll
        for (int ti = 0; ti < NTI; ++ti) {
            float xsv[4] = {xs[ti].x, xs[ti].y, xs[ti].z, xs[ti].w};
#pragma unroll
            for (int tj = 0; tj < 4; ++tj)
#pragma unroll
                for (int rg = 0; rg < 4; ++rg)
                    insertK<MPCL>(ls[tj], li[tj], acc[ti][tj][rg] + xsv[rg],
                                  pb + ti * 16 + quad * 4 + rg);
        }
    }

    // ---- block merge: 16 cell-lists per query -> top-8 per (query,chunk) ----
    __syncthreads();   // Q no longer needed; reuse LDS
#pragma unroll
    for (int tj = 0; tj < 4; ++tj)
#pragma unroll
        for (int r = 0; r < MPCL; ++r) {
            u.mg.ms[tj * 16 + l15][wave * 4 + quad][r] = ls[tj][r];
            u.mg.mi[tj * 16 + l15][wave * 4 + quad][r] = li[tj][r];
        }
    __syncthreads();
    if (tid < QB) {
        float fs[MPC]; int fi[MPC];
#pragma unroll
        for (int r = 0; r < MPC; ++r) { fs[r] = FLT_MAX; fi[r] = -1; }
        for (int c = 0; c < 16; ++c)
#pragma unroll
            for (int r = 0; r < MPCL; ++r)
                insertK<MPC>(fs, fi, u.mg.ms[tid][c][r], u.mg.mi[tid][c][r]);
        size_t base = ((size_t)(qt * QB + tid) * NCH + chunk) * MPC;
#pragma unroll
        for (int r = 0; r < MPC; ++r) { candS[base + r] = fs[r]; candI[base + r] = fi[r]; }
    }
}

// Per query: 448 candidates -> per-lane sorted 7 -> wave pop-merge top-16 ->
// exact fp32 rescore -> exact top-5 -> gather + mean.
__global__ void rescore_kernel(const float* __restrict__ Q, const float* __restrict__ X,
                               const float* __restrict__ xsq,
                               const float* __restrict__ candS, const int* __restrict__ candI,
                               float* __restrict__ out) {
    const int b = blockIdx.x;
    const int tid = threadIdx.x;
    const int wave = tid >> 6;
    const int lane = tid & 63;
    __shared__ int exI[TR];
    __shared__ float exS[TR];
    __shared__ int top5[5];

    if (wave == 0) {
        const float* cs = candS + (size_t)b * CPQ;
        const int* ci = candI + (size_t)b * CPQ;
        float as[7]; int ai[7];
#pragma unroll
        for (int r = 0; r < 7; ++r) { as[r] = FLT_MAX; ai[r] = -1; }
#pragma unroll
        for (int j = 0; j < 7; ++j)
            insertK<7>(as, ai, cs[lane * 7 + j], ci[lane * 7 + j]);
        for (int r = 0; r < TR; ++r) {
            float v = as[0]; int wl = lane;
#pragma unroll
            for (int off = 1; off < 64; off <<= 1) {
                float ov = __shfl_xor(v, off, 64);
                int owl = __shfl_xor(wl, off, 64);
                if (ov < v || (ov == v && owl < wl)) { v = ov; wl = owl; }
            }
            if (lane == wl) {
                exI[r] = ai[0];
#pragma unroll
                for (int z = 0; z < 6; ++z) { as[z] = as[z + 1]; ai[z] = ai[z + 1]; }
                as[6] = FLT_MAX;
            }
        }
    }
    __syncthreads();

    const float* qr = Q + (size_t)b * D;
#pragma unroll
    for (int cc = 0; cc < 4; ++cc) {
        int c = wave * 4 + cc;
        int idx = exI[c];
        const float* xr = X + (size_t)idx * D;
        float4 qa = *(const float4*)(qr + lane * 8);
        float4 qb = *(const float4*)(qr + lane * 8 + 4);
        float4 xa = *(const float4*)(xr + lane * 8);
        float4 xb = *(const float4*)(xr + lane * 8 + 4);
        float p = qa.x * xa.x + qa.y * xa.y + qa.z * xa.z + qa.w * xa.w
                + qb.x * xb.x + qb.y * xb.y + qb.z * xb.z + qb.w * xb.w;
#pragma unroll
        for (int off = 32; off > 0; off >>= 1) p += __shfl_down(p, off, 64);
        if (lane == 0) exS[c] = xsq[idx] - 2.0f * p;
    }
    __syncthreads();

    if (tid == 0) {
        float fs[5]; int fi[5];
#pragma unroll
        for (int r = 0; r < 5; ++r) { fs[r] = FLT_MAX; fi[r] = -1; }
        for (int i = 0; i < TR; ++i) insertK<5>(fs, fi, exS[i], exI[i]);
#pragma unroll
        for (int r = 0; r < 5; ++r) top5[r] = fi[r];
    }
    __syncthreads();

#pragma unroll
    for (int dd = 0; dd < 2; ++dd) {
        int d = tid + dd * 256;
        float s = 0.0f;
#pragma unroll
        for (int r = 0; r < 5; ++r) s += X[(size_t)top5[r] * D + d];
        out[(size_t)b * D + d] = s / 5.0f;
    }
}

extern "C" void kernel_launch(void* const* d_in, const int* in_sizes, int n_in,
                              void* d_out, int out_size, void* d_ws, size_t ws_size,
                              hipStream_t stream) {
    const float* x_enc = (const float*)d_in[0];
    const float* X_fit = (const float*)d_in[1];
    float* out = (float*)d_out;
    const int B = in_sizes[0] / D;               // 2048
    const int N = in_sizes[1] / D;               // 100000
    const int padN = ((N + PT - 1) / PT) * PT;   // 100352 = NCH*TPC*PT

    char* w = (char*)d_ws;
    unsigned char* Xp = (unsigned char*)w;               w += (size_t)padN * 512;  // 51.4 MB
    unsigned char* Qp = (unsigned char*)w;               w += (size_t)B * 512;     // 1 MB
    float* xsq = (float*)w;                              w += (size_t)padN * 4;
    float* candS = (float*)w;                            w += (size_t)B * CPQ * 4;
    int* candI = (int*)w;

    hipLaunchKernelGGL(convert_x, dim3(padN / 4), dim3(256), 0, stream, X_fit, Xp, xsq, N, padN);
    hipLaunchKernelGGL(convert_q, dim3(B / 4), dim3(256), 0, stream, x_enc, Qp);
    hipLaunchKernelGGL(score_mfma, dim3(NCH * 32), dim3(256), 0, stream,
                       Qp, Xp, xsq, candS, candI);
    hipLaunchKernelGGL(rescore_kernel, dim3(B), dim3(256), 0, stream,
                       x_enc, X_fit, xsq, candS, candI, out);
}